// Round 18
// baseline (333.220 us; speedup 1.0000x reference)
//
#include <hip/hip_runtime.h>
#include <math.h>

// Problem constants (from setup_inputs: N_data=2000, Lt=10, Q=8, M=256, D=16)
#define NH   2000     // Hankel rows == Y rows
#define QD   8        // latent dim Q
#define DIN  80       // Lt*Q
#define MI   256      // inducing points
#define DOUT 16       // output dim D
#define SIGMA2     1e-3f
#define INV_SIGMA2 1000.0f
#define JITTER     1e-4f

// HARD-WON NOTES (rounds 1-17):
//  - per-thread arrays indexed dynamically -> scratch (4 ms).
//  - LARGE (64-float) register tiles across barriered loops spill; 4x4 cells
//    do NOT spill even across barriered serial loops.
//  - factorization serial loops cost ~1.2k cy/step; the lever is the NUMBER
//    of steps: r9 augmented [A|I] (128->64), r13 rank-2 (64->32 barriers).
//  - latency chains: single-wg kernels with serial load loops (r5 k_prep).
//  - parallelism-starved kernels: split-K until >= 1.5 blocks/CU.
//  - DEVICE ATOMICS ARE EXPENSIVE (r12): partial buffers + plain stores.
//  - r10 bug: LDS staging with `if (tid < N)` when N > blockDim -> poison.
//  - workspace is NOT zeroed (0xAA poison): every buffer fully written.
//  - r15: Z (80 KB) is cache-resident; coalescing was neutral.
//  - r16: stride-64 LDS tiles = 16-way conflicts; pad to 68. BUT (r17):
//    64^3 GEMM round = 512 KB LDS reads = ~1.7 us/round PER CU. Never
//    serialize a multi-round GEMM chain into one block if launches can
//    spread the rounds across CUs (toff2 merge: 45 us vs 3-launch ~22 us).

// acc layout: [0..7] sum(Y^2) partials, [8..11] logdet-K, [12..15] logdet-M

// ------ merged: vbar (b<80) | sum(Y^2) (80<=b<88) | Zt transpose (b>=88) ----
__global__ void k_pre(const float* __restrict__ Xm_v, const float* __restrict__ Y,
                      const float* __restrict__ Z, const float* __restrict__ ls,
                      float* __restrict__ vbar, float* __restrict__ Zt,
                      float* __restrict__ acc) {
    __shared__ float red[256];
    int tid = threadIdx.x;
    int b = blockIdx.x;
    if (b >= DIN + 8) {                       // transpose path
        int j = b - (DIN + 8);
        Zt[j * MI + tid] = Z[tid * DIN + j];
        return;
    }
    if (b < DIN) {
        int j = b;
        int l = j >> 3, qq = j & 7;
        float lsv = ls[j];
        float ls2 = lsv * lsv;
        float s = 0.f;
        for (int n = tid; n < NH; n += 256) {
            float xv = Xm_v[(1 + n + l) * QD + qq];
            s += 1.0f / (2.0f * xv + ls2);
        }
        red[tid] = s;
        __syncthreads();
        for (int st = 128; st > 0; st >>= 1) {
            if (tid < st) red[tid] += red[tid + st];
            __syncthreads();
        }
        if (tid == 0) vbar[j] = red[0] * (1.0f / NH);
    } else {
        const float4* y4 = (const float4*)Y;
        float sy = 0.f;
        for (int i = (b - DIN) * 256 + tid; i < NH * DOUT / 4; i += 8 * 256) {
            float4 y = y4[i];
            sy += y.x * y.x + y.y * y.y + y.z * y.z + y.w * y.w;
        }
        red[tid] = sy;
        __syncthreads();
        for (int st = 128; st > 0; st >>= 1) {
            if (tid < st) red[tid] += red[tid + st];
            __syncthreads();
        }
        if (tid == 0) acc[b - DIN] = red[0];
    }
}

// ------ merged: psi1/Eg rows (n<2000) | Kuu+F rows (n>=2000) ----------------
__global__ void k_mainkuu(const float* __restrict__ Xm_m, const float* __restrict__ Xm_v,
                          const float* __restrict__ Zt, const float* __restrict__ Z,
                          const float* __restrict__ ls, const float* __restrict__ vbar,
                          const float* __restrict__ kvp,
                          float* __restrict__ psi1, float* __restrict__ Eg,
                          float* __restrict__ Kuu, float* __restrict__ F) {
    __shared__ float xm[DIN], h1[DIN], v2[DIN];
    __shared__ float red1[DIN], red2[DIN];
    __shared__ float sc[2];
    int tid = threadIdx.x;
    int n = blockIdx.x;
    if (n < NH) {
        if (tid < DIN) {
            int j = tid;
            int l = j >> 3, qq = j & 7;
            int row = 1 + n + l;                       // hankel(v[1:], Lt)
            float xmv = Xm_m[row * QD + qq];
            float xvv = Xm_v[row * QD + qq];
            float lsv = ls[j];
            float ls2 = lsv * lsv;
            float iv1 = 1.0f / (xvv + ls2);
            float iv2 = 1.0f / (2.0f * xvv + ls2);
            xm[j] = xmv; h1[j] = 0.5f * iv1; v2[j] = iv2;
            red1[j] = 0.5f * __logf(ls2 * iv1);
            red2[j] = 0.25f * __logf(ls2 * iv2) - 0.5f * xmv * xmv * iv2;
        }
        __syncthreads();
        if (tid == 0) {
            float a = 0.f, b = 0.f;
            for (int j = 0; j < DIN; ++j) { a += red1[j]; b += red2[j]; }
            sc[0] = a; sc[1] = b;
        }
        __syncthreads();
        float c1 = sc[0], c2h = sc[1];
        float e1h = 0.f, P = 0.f;
        #pragma unroll 8
        for (int j = 0; j < DIN; ++j) {
            float z = Zt[j * MI + tid];
            float d = z - xm[j];
            e1h += h1[j] * d * d;
            P += v2[j] * z * (0.25f * z - xm[j]);
        }
        float kv = kvp[0];
        psi1[n * MI + tid] = kv * __expf(c1 - e1h);
        Eg [n * MI + tid] = __expf(c2h - P);
    } else {
        int b = n - NH;
        if (tid < DIN) {
            float l = ls[tid];
            xm[tid] = 1.0f / (l * l);        // ils2
            h1[tid] = Z[b * DIN + tid];      // zb row
            v2[tid] = vbar[tid];
        }
        __syncthreads();
        float d2a = 0.f, c0 = 0.f;
        #pragma unroll 8
        for (int j = 0; j < DIN; ++j) {
            float za = Zt[j * MI + tid];
            float zb = h1[j];
            float d = za - zb;
            d2a += d * d * xm[j];
            c0 += v2[j] * za * zb;
        }
        float kv = kvp[0];
        int a = tid;
        Kuu[b * MI + a] = kv * __expf(-0.5f * d2a) + (a == b ? JITTER : 0.f);
        F  [b * MI + a] = kv * kv * __expf(-0.25f * d2a - 0.5f * c0);
    }
}

// ------ merged: split-K SYRK (bx < 16*nsplit) | Gpart (bx >= 16*nsplit) -----
__global__ void k_syrkG(const float* __restrict__ Eg, const float* __restrict__ psi1,
                        const float* __restrict__ Y,
                        float* __restrict__ Spart, float* __restrict__ Gpart,
                        int nsplit, int rowsPer) {
    __shared__ __align__(16) float As[16 * 64], Bs[16 * 64];
    int tid = threadIdx.x;
    int bx = blockIdx.x;
    if (bx < 16 * nsplit) {
        int tile = bx & 15, y = bx >> 4;
        int ta = tile & 3, tb = tile >> 2;
        int k0 = y * rowsPer;
        int tx = tid & 15, ty = tid >> 4;
        float acc[4][4] = {};
        for (int kk = k0; kk < k0 + rowsPer; kk += 16) {
            __syncthreads();
            for (int i = tid; i < 1024; i += 256) {
                int k = i >> 6, c = i & 63;
                As[k * 64 + c] = Eg[(kk + k) * MI + 64 * ta + c];
                Bs[k * 64 + c] = Eg[(kk + k) * MI + 64 * tb + c];
            }
            __syncthreads();
            #pragma unroll
            for (int k = 0; k < 16; ++k) {
                float4 a4 = *(const float4*)&As[k * 64 + 4 * tx];
                float4 b4 = *(const float4*)&Bs[k * 64 + 4 * ty];
                float a[4] = {a4.x, a4.y, a4.z, a4.w};
                float b[4] = {b4.x, b4.y, b4.z, b4.w};
                #pragma unroll
                for (int i = 0; i < 4; ++i)
                    #pragma unroll
                    for (int j = 0; j < 4; ++j)
                        acc[i][j] += a[i] * b[j];
            }
        }
        float* out = Spart + y * (MI * MI);
        #pragma unroll
        for (int i = 0; i < 4; ++i)
            #pragma unroll
            for (int j = 0; j < 4; ++j)
                out[(64 * ta + 4 * tx + i) * MI + 64 * tb + 4 * ty + j] = acc[i][j];
    } else {
        int gb = bx - 16 * nsplit;           // 0..79
        float* Ys = As;                       // reuse LDS
        int n0 = gb * 25;
        for (int i = tid; i < 25 * DOUT; i += 256) Ys[i] = Y[n0 * DOUT + i];
        __syncthreads();
        float acc[DOUT] = {};
        #pragma unroll
        for (int m = 0; m < 25; ++m) {
            float p = psi1[(n0 + m) * MI + tid];
            #pragma unroll
            for (int d = 0; d < DOUT; ++d) acc[d] += p * Ys[m * DOUT + d];
        }
        float4* out = (float4*)(Gpart + gb * (MI * DOUT) + tid * DOUT);
        out[0] = make_float4(acc[0], acc[1], acc[2], acc[3]);
        out[1] = make_float4(acc[4], acc[5], acc[6], acc[7]);
        out[2] = make_float4(acc[8], acc[9], acc[10], acc[11]);
        out[3] = make_float4(acc[12], acc[13], acc[14], acc[15]);
    }
}

// ------ merged: S/M2 assembly (bx<256) | Gsum (bx>=256) ---------------------
__global__ void k_psi2MG(const float* __restrict__ F, const float* __restrict__ Spart,
                         const float* __restrict__ Kuu, const float* __restrict__ Gpart,
                         float* __restrict__ S, float* __restrict__ M2,
                         float* __restrict__ G, int nsplit) {
    int tid = threadIdx.x;
    int bx = blockIdx.x;
    if (bx < 256) {
        int i = bx * 256 + tid;
        float s = 0.f;
        for (int y = 0; y < nsplit; ++y) s += Spart[y * (MI * MI) + i];
        float v = F[i] * s;
        S[i] = v;
        M2[i] = Kuu[i] + INV_SIGMA2 * v;
    } else {
        int gid = (bx - 256) * 256 + tid;
        float s = 0.f;
        for (int b = 0; b < 80; ++b) s += Gpart[b * (MI * DOUT) + gid];
        G[gid] = s;
    }
}

// ------- 64x64 diag: augmented [A|I], RANK-2, + fused panel TRSM ------------
__global__ void k_dchol(float* __restrict__ AK, float* __restrict__ AM,
                        float* __restrict__ LiK, float* __restrict__ LiM,
                        float* __restrict__ acc, int p) {
    float* A  = blockIdx.x ? AM : AK;
    float* Li = blockIdx.x ? LiM : LiK;
    const int c0 = 64 * p;
    __shared__ float colA[2][64], colB[2][64];
    __shared__ float rowEA[2][64], rowEB[2][64];
    __shared__ float isr[64];
    __shared__ float LsT[64 * 68];      // LsT[c*68+r] = Linv[r][c]
    __shared__ float As[64 * 68];       // As[k*68+r] = A21[r][k]
    int tid = threadIdx.x;              // 512
    int tx = tid & 15;
    int ty = tid >> 4;
    bool isA = ty < 16;
    int cb = isA ? 4 * ty : 4 * (ty - 16);
    float t[4][4];
    if (isA) {
        #pragma unroll
        for (int i = 0; i < 4; ++i)
            #pragma unroll
            for (int j = 0; j < 4; ++j)
                t[i][j] = A[(c0 + 4 * tx + i) * MI + c0 + cb + j];
    } else {
        #pragma unroll
        for (int i = 0; i < 4; ++i)
            #pragma unroll
            for (int j = 0; j < 4; ++j)
                t[i][j] = (4 * tx + i == cb + j) ? 1.f : 0.f;
    }
    if (isA && ty == 0) {
        #pragma unroll
        for (int i = 0; i < 4; ++i) {
            colA[0][4 * tx + i] = t[i][0];
            colB[0][4 * tx + i] = t[i][1];
        }
    }
    if (tid < 64) {
        rowEA[0][tid] = (tid == 0) ? 1.f : 0.f;
        rowEB[0][tid] = (tid == 1) ? 1.f : 0.f;
    }
    __syncthreads();
    float lgsum = 0.f;
    for (int s = 0; s < 32; ++s) {
        int pb = s & 1;
        int k0 = 2 * s, k1 = 2 * s + 1;
        float pk0 = colA[pb][k0];
        float ip0 = 1.0f / pk0;
        float m10 = colA[pb][k1] * ip0;
        float pk1 = colB[pb][k1] - m10 * colA[pb][k1];
        float ip1 = 1.0f / pk1;
        if (tid == 0) {
            isr[k0] = rsqrtf(pk0); isr[k1] = rsqrtf(pk1);
            lgsum += __logf(pk0) + __logf(pk1);
        }
        float a0[4], a1[4], b0[4], b1[4];
        #pragma unroll
        for (int i = 0; i < 4; ++i) {
            int r = 4 * tx + i;
            float cA = colA[pb][r], cB = colB[pb][r];
            a0[i] = (r > k0) ? cA * ip0 : 0.f;
            a1[i] = (r > k1) ? (cB - m10 * cA) * ip1 : 0.f;
        }
        if (isA) {
            #pragma unroll
            for (int j = 0; j < 4; ++j) {
                int c = cb + j;
                float cA = colA[pb][c], cB = colB[pb][c];
                b0[j] = (c > k0) ? cA : 0.f;
                b1[j] = (c > k1) ? (cB - m10 * cA) : 0.f;
            }
        } else {
            #pragma unroll
            for (int j = 0; j < 4; ++j) {
                float eA = rowEA[pb][cb + j], eB = rowEB[pb][cb + j];
                b0[j] = eA;
                b1[j] = eB - m10 * eA;
            }
        }
        #pragma unroll
        for (int i = 0; i < 4; ++i)
            #pragma unroll
            for (int j = 0; j < 4; ++j) {
                t[i][j] = fmaf(-a0[i], b0[j], t[i][j]);
                t[i][j] = fmaf(-a1[i], b1[j], t[i][j]);
            }
        if (s < 31) {
            int kn0 = k0 + 2;
            if (isA && ty == (kn0 >> 2)) {
                int j0 = kn0 & 3;
                #pragma unroll
                for (int jj = 0; jj < 4; ++jj) {
                    if (jj == j0) {
                        #pragma unroll
                        for (int i = 0; i < 4; ++i) colA[1 - pb][4 * tx + i] = t[i][jj];
                    }
                    if (jj == j0 + 1) {
                        #pragma unroll
                        for (int i = 0; i < 4; ++i) colB[1 - pb][4 * tx + i] = t[i][jj];
                    }
                }
            }
            if (!isA && tx == (kn0 >> 2)) {
                int i0 = kn0 & 3;
                #pragma unroll
                for (int ii = 0; ii < 4; ++ii) {
                    if (ii == i0) {
                        #pragma unroll
                        for (int j = 0; j < 4; ++j) rowEA[1 - pb][cb + j] = t[ii][j];
                    }
                    if (ii == i0 + 1) {
                        #pragma unroll
                        for (int j = 0; j < 4; ++j) rowEB[1 - pb][cb + j] = t[ii][j];
                    }
                }
            }
        }
        __syncthreads();
    }
    if (tid == 0) acc[8 + 4 * blockIdx.x + p] = lgsum;
    if (!isA) {
        #pragma unroll
        for (int i = 0; i < 4; ++i) {
            int r = 4 * tx + i;
            float sc = isr[r];
            #pragma unroll
            for (int j = 0; j < 4; ++j) {
                float v = t[i][j] * sc;
                Li[(c0 + r) * MI + c0 + cb + j] = v;
                LsT[(cb + j) * 68 + r] = v;
            }
        }
    }
    for (int jb = p + 1; jb < 4; ++jb)
        for (int q = tid; q < 4096; q += 512) {
            int rr = q >> 6, cc = q & 63;
            Li[(c0 + rr) * MI + 64 * jb + cc] = 0.f;
        }
    if (p < 3) {
        __syncthreads();
        for (int rb = 0; rb < 3 - p; ++rb) {
            int R0 = c0 + 64 + 64 * rb;
            for (int q = tid; q < 4096; q += 512) {
                int rr = q >> 6, k = q & 63;
                As[k * 68 + rr] = A[(R0 + rr) * MI + c0 + k];
            }
            __syncthreads();
            if (tid < 256) {
                int txc = tid & 15, tyc = tid >> 4;
                float acc4[4][4] = {};
                #pragma unroll 4
                for (int k = 0; k < 64; ++k) {
                    float4 a4 = *(const float4*)&As[k * 68 + 4 * txc];
                    float4 b4 = *(const float4*)&LsT[k * 68 + 4 * tyc];
                    float a[4] = {a4.x, a4.y, a4.z, a4.w};
                    float b[4] = {b4.x, b4.y, b4.z, b4.w};
                    #pragma unroll
                    for (int i = 0; i < 4; ++i)
                        #pragma unroll
                        for (int j = 0; j < 4; ++j)
                            acc4[i][j] += a[i] * b[j];
                }
                #pragma unroll
                for (int i = 0; i < 4; ++i)
                    #pragma unroll
                    for (int j = 0; j < 4; ++j)
                        A[(R0 + 4 * txc + i) * MI + c0 + 4 * tyc + j] = acc4[i][j];
            }
            __syncthreads();
        }
    }
}

// ---------------- trailing update: A22 -= Lp * Lp^T (64x64x64 tiles) --------
__global__ void k_cholu(float* __restrict__ AK, float* __restrict__ AM, int p) {
    float* A = blockIdx.y ? AM : AK;
    int t0 = 64 * (p + 1);
    int idx = blockIdx.x, ti = 0;
    while (idx > ti) { idx -= ti + 1; ti++; }
    int tj = idx;
    int R0 = t0 + 64 * ti, C0 = t0 + 64 * tj, K0 = 64 * p;
    __shared__ float As[64 * 68], Bs[64 * 68];
    int tid = threadIdx.x;
    int tx = tid & 15, ty = tid >> 4;
    for (int q = tid; q < 4096; q += 256) {
        int rr = q >> 6, k = q & 63;
        As[k * 68 + rr] = A[(R0 + rr) * MI + K0 + k];
        Bs[k * 68 + rr] = A[(C0 + rr) * MI + K0 + k];
    }
    __syncthreads();
    float acc[4][4] = {};
    #pragma unroll 4
    for (int k = 0; k < 64; ++k) {
        float4 a4 = *(const float4*)&As[k * 68 + 4 * tx];
        float4 b4 = *(const float4*)&Bs[k * 68 + 4 * ty];
        float a[4] = {a4.x, a4.y, a4.z, a4.w};
        float b[4] = {b4.x, b4.y, b4.z, b4.w};
        #pragma unroll
        for (int i = 0; i < 4; ++i)
            #pragma unroll
            for (int j = 0; j < 4; ++j)
                acc[i][j] += a[i] * b[j];
    }
    #pragma unroll
    for (int i = 0; i < 4; ++i)
        #pragma unroll
        for (int j = 0; j < 4; ++j) {
            int g = (R0 + 4 * tx + i) * MI + C0 + 4 * ty + j;
            A[g] -= acc[i][j];
        }
}

// ---- off-diagonal Linv blocks at distance d: X_ij = -Linv_ii * sum L_ik X_kj
// 3 launches (d=1..3); (4-d)x2 blocks each -> rounds spread across CUs.
__global__ void k_toff(const float* __restrict__ LAK, const float* __restrict__ LAM,
                       float* __restrict__ LiK, float* __restrict__ LiM, int d) {
    const float* LA = blockIdx.y ? LAM : LAK;
    float* Li = blockIdx.y ? LiM : LiK;
    int j = blockIdx.x, i = j + d;
    __shared__ float As[64 * 68], Bs[64 * 68];
    int tid = threadIdx.x;
    int tx = tid & 15, ty = tid >> 4;
    float acc[4][4] = {};
    for (int m = 0; m < d; ++m) {
        int kb = j + m;
        __syncthreads();
        for (int q = tid; q < 4096; q += 256) {
            int rr = q >> 6, k = q & 63;
            As[k * 68 + rr] = LA[(64 * i + rr) * MI + 64 * kb + k];
        }
        for (int q = tid; q < 4096; q += 256) {
            int k = q >> 6, c = q & 63;
            Bs[k * 68 + c] = Li[(64 * kb + k) * MI + 64 * j + c];
        }
        __syncthreads();
        #pragma unroll 4
        for (int k = 0; k < 64; ++k) {
            float4 a4 = *(const float4*)&As[k * 68 + 4 * tx];
            float4 b4 = *(const float4*)&Bs[k * 68 + 4 * ty];
            float a[4] = {a4.x, a4.y, a4.z, a4.w};
            float b[4] = {b4.x, b4.y, b4.z, b4.w};
            #pragma unroll
            for (int i2 = 0; i2 < 4; ++i2)
                #pragma unroll
                for (int j2 = 0; j2 < 4; ++j2)
                    acc[i2][j2] += a[i2] * b[j2];
        }
    }
    __syncthreads();
    #pragma unroll
    for (int i2 = 0; i2 < 4; ++i2)
        #pragma unroll
        for (int j2 = 0; j2 < 4; ++j2)
            Bs[(4 * tx + i2) * 68 + 4 * ty + j2] = acc[i2][j2];
    for (int q = tid; q < 4096; q += 256) {
        int rr = q >> 6, k = q & 63;
        As[k * 68 + rr] = Li[(64 * i + rr) * MI + 64 * i + k];
    }
    __syncthreads();
    float out[4][4] = {};
    #pragma unroll 4
    for (int k = 0; k < 64; ++k) {
        float4 a4 = *(const float4*)&As[k * 68 + 4 * tx];
        float4 b4 = *(const float4*)&Bs[k * 68 + 4 * ty];
        float a[4] = {a4.x, a4.y, a4.z, a4.w};
        float b[4] = {b4.x, b4.y, b4.z, b4.w};
        #pragma unroll
        for (int i2 = 0; i2 < 4; ++i2)
            #pragma unroll
            for (int j2 = 0; j2 < 4; ++j2)
                out[i2][j2] += a[i2] * b[j2];
    }
    #pragma unroll
    for (int i2 = 0; i2 < 4; ++i2)
        #pragma unroll
        for (int j2 = 0; j2 < 4; ++j2)
            Li[(64 * i + 4 * tx + i2) * MI + 64 * j + 4 * ty + j2] = -out[i2][j2];
}

// -------- trace partials: Tpart[slot] = <Li_tile * S_slab, Li_tile> ---------
__global__ void k_trace(const float* __restrict__ Li, const float* __restrict__ S,
                        float* __restrict__ Tpart) {
    int R = 64 * (blockIdx.x >> 2), C = 64 * (blockIdx.x & 3);
    int k0 = 16 * blockIdx.y;
    int slot = blockIdx.y * 16 + blockIdx.x;
    if (C > R || k0 >= R + 64) {
        if (threadIdx.x == 0) Tpart[slot] = 0.f;
        return;
    }
    __shared__ __align__(16) float As[16 * 68], Bs[16 * 68];
    __shared__ float red[256];
    int tid = threadIdx.x;
    int tx = tid & 15, ty = tid >> 4;
    for (int q = tid; q < 1024; q += 256) {
        int rr = q >> 4, kk = q & 15;
        As[kk * 68 + rr] = Li[(R + rr) * MI + k0 + kk];
    }
    for (int q = tid; q < 1024; q += 256) {
        int kk = q >> 6, c = q & 63;
        Bs[kk * 68 + c] = S[(k0 + kk) * MI + C + c];
    }
    __syncthreads();
    float acc4[4][4] = {};
    #pragma unroll
    for (int k = 0; k < 16; ++k) {
        float4 a4 = *(const float4*)&As[k * 68 + 4 * tx];
        float4 b4 = *(const float4*)&Bs[k * 68 + 4 * ty];
        float a[4] = {a4.x, a4.y, a4.z, a4.w};
        float b[4] = {b4.x, b4.y, b4.z, b4.w};
        #pragma unroll
        for (int i = 0; i < 4; ++i)
            #pragma unroll
            for (int j = 0; j < 4; ++j)
                acc4[i][j] += a[i] * b[j];
    }
    float ts = 0.f;
    #pragma unroll
    for (int i = 0; i < 4; ++i)
        #pragma unroll
        for (int j = 0; j < 4; ++j)
            ts += acc4[i][j] * Li[(R + 4 * tx + i) * MI + C + 4 * ty + j];
    red[tid] = ts;
    __syncthreads();
    for (int st = 128; st > 0; st >>= 1) {
        if (tid < st) red[tid] += red[tid + st];
        __syncthreads();
    }
    if (tid == 0) Tpart[slot] = red[0];
}

// -------- w = LinvM*G ; sum Tpart + acc slots ; assemble bound ----------
__global__ void k_final(const float* __restrict__ LiM, const float* __restrict__ G,
                        const float* __restrict__ Tpart,
                        const float* __restrict__ accbuf, const float* __restrict__ kvp,
                        float* __restrict__ out) {
    __shared__ float Gs[MI * DOUT];
    __shared__ float red[256], redT[256];
    __shared__ float accs[16];
    int tid = threadIdx.x;
    for (int i = tid; i < MI * DOUT; i += 256) Gs[i] = G[i];
    redT[tid] = Tpart[tid];
    if (tid < 16) accs[tid] = accbuf[tid];
    __syncthreads();
    float w[DOUT] = {};
    const float4* lrow4 = (const float4*)(LiM + tid * MI);
    for (int k4 = 0; k4 < MI / 4; ++k4) {
        float4 l = lrow4[k4];
        const float* g0 = &Gs[(4 * k4) * DOUT];
        #pragma unroll
        for (int d = 0; d < DOUT; ++d)
            w[d] += l.x * g0[d] + l.y * g0[DOUT + d] + l.z * g0[2 * DOUT + d] + l.w * g0[3 * DOUT + d];
    }
    float c2 = 0.f;
    #pragma unroll
    for (int d = 0; d < DOUT; ++d) c2 += w[d] * w[d];
    red[tid] = c2;
    __syncthreads();
    for (int st = 128; st > 0; st >>= 1) {
        if (tid < st) { red[tid] += red[tid + st]; redT[tid] += redT[tid + st]; }
        __syncthreads();
    }
    if (tid == 0) {
        float kv = kvp[0];
        float sumY2 = 0.f, ldK = 0.f, ldM = 0.f;
        for (int i = 0; i < 8; ++i) sumY2 += accs[i];
        for (int i = 8; i < 12; ++i) ldK += accs[i];
        for (int i = 12; i < 16; ++i) ldM += accs[i];
        float trace = redT[0] * INV_SIGMA2;
        float logdetB = ldM - ldK;
        float bound = -0.5f * (float)(NH * DOUT) * __logf(6.28318530717959f * SIGMA2)
                      - 0.5f * INV_SIGMA2 * sumY2
                      - 0.5f * (float)DOUT * ((float)NH * kv * INV_SIGMA2 - trace)
                      - 0.5f * (float)DOUT * logdetB
                      + 0.5f * 1.0e6f * red[0];
        out[0] = bound;
    }
}

extern "C" void kernel_launch(void* const* d_in, const int* in_sizes, int n_in,
                              void* d_out, int out_size, void* d_ws, size_t ws_size,
                              hipStream_t stream) {
    (void)in_sizes; (void)n_in; (void)out_size;
    const float* Xm_m = (const float*)d_in[0];
    const float* Xm_v = (const float*)d_in[1];
    const float* Z    = (const float*)d_in[2];
    const float* Y    = (const float*)d_in[3];
    const float* kvp  = (const float*)d_in[4];
    const float* ls   = (const float*)d_in[5];
    float* out = (float*)d_out;
    float* W = (float*)d_ws;

    float* acc   = W;              // 16 slots
    float* Tpart = W + 16;         // 256
    float* G     = W + 272;        // 4096
    float* LinvK = W + 4368;       // 65536
    float* LinvM = W + 69904;      // 65536
    float* vbar  = W + 135440;     // 80
    float* psi1  = W + 135520;     // 512000
    float* Eg    = W + 647520;     // 512000
    float* Kuu   = W + 1159520;    // 65536
    float* M2    = W + 1225056;    // 65536
    float* S     = W + 1290592;    // 65536
    float* F     = W + 1356128;    // 65536
    float* Zt    = W + 1421664;    // 20480
    float* Spart = W + 1442144;    // nsplit*65536
    // Gpart follows Spart: 80*4096 floats

    int nsplit = (ws_size >= (size_t)(1442144 + 25 * 65536 + 80 * 4096) * 4) ? 25 : 5;
    int rowsPer = NH / nsplit;
    float* Gpart = Spart + (size_t)nsplit * 65536;

    k_pre<<<DIN + 8 + DIN, 256, 0, stream>>>(Xm_v, Y, Z, ls, vbar, Zt, acc);
    k_mainkuu<<<NH + MI, 256, 0, stream>>>(Xm_m, Xm_v, Zt, Z, ls, vbar, kvp,
                                           psi1, Eg, Kuu, F);
    k_syrkG<<<16 * nsplit + 80, 256, 0, stream>>>(Eg, psi1, Y, Spart, Gpart,
                                                  nsplit, rowsPer);
    k_psi2MG<<<272, 256, 0, stream>>>(F, Spart, Kuu, Gpart, S, M2, G, nsplit);

    // batched blocked Cholesky (rank-2 augmented diag + fused TRSM) of {Kuu, M2}
    for (int p = 0; p < 4; ++p) {
        k_dchol<<<2, 512, 0, stream>>>(Kuu, M2, LinvK, LinvM, acc, p);
        if (p < 3) {
            int nt = 3 - p;
            k_cholu<<<dim3(nt * (nt + 1) / 2, 2), 256, 0, stream>>>(Kuu, M2, p);
        }
    }
    // off-diagonal Linv blocks: 3 launches, distances spread across CUs
    for (int d = 1; d < 4; ++d)
        k_toff<<<dim3(4 - d, 2), 256, 0, stream>>>(Kuu, M2, LinvK, LinvM, d);

    k_trace<<<dim3(16, 16), 256, 0, stream>>>(LinvK, S, Tpart);
    k_final<<<1, 256, 0, stream>>>(LinvM, G, Tpart, acc, kvp, out);
}

// Round 19
// 303.767 us; speedup vs baseline: 1.0970x; 1.0970x over previous
//
#include <hip/hip_runtime.h>
#include <math.h>

// Problem constants (from setup_inputs: N_data=2000, Lt=10, Q=8, M=256, D=16)
#define NH   2000     // Hankel rows == Y rows
#define QD   8        // latent dim Q
#define DIN  80       // Lt*Q
#define MI   256      // inducing points
#define DOUT 16       // output dim D
#define SIGMA2     1e-3f
#define INV_SIGMA2 1000.0f
#define JITTER     1e-4f

// HARD-WON NOTES (rounds 1-18):
//  - per-thread arrays indexed dynamically -> scratch (4 ms).
//  - LARGE (64-float) register tiles across barriered loops spill; 4x4 cells
//    do NOT spill even across barriered serial loops.
//  - factorization serial loops cost ~1.2k cy/step; the lever is the NUMBER
//    of steps: r9 augmented [A|I] (128->64), r13 rank-2 (64->32 barriers).
//  - latency chains: single-wg kernels with serial load loops (r5 k_prep).
//  - parallelism-starved kernels: split-K until >= 1.5 blocks/CU.
//  - DEVICE ATOMICS ARE EXPENSIVE (r12): partial buffers + plain stores.
//  - r10 bug: LDS staging with `if (tid < N)` when N > blockDim -> poison.
//  - workspace is NOT zeroed (0xAA poison): every buffer fully written.
//  - r15: Z (80 KB) is cache-resident; coalescing was neutral.
//  - r16: stride-64 LDS tiles = 16-way conflicts; pad to 68.
//  - r18 A/B: a serialized launch gap costs ~10 us on this harness; merging
//    a dependency chain into ONE kernel wins even if the merged kernel is
//    individually 2x slower (toff2 45us single-launch beats 3 launches:
//    totals 306 vs 333). Keep toff2.

// acc layout: [0..7] sum(Y^2) partials, [8..11] logdet-K, [12..15] logdet-M

// ------ merged: vbar (b<80) | sum(Y^2) (80<=b<88) | Zt transpose (b>=88) ----
__global__ void k_pre(const float* __restrict__ Xm_v, const float* __restrict__ Y,
                      const float* __restrict__ Z, const float* __restrict__ ls,
                      float* __restrict__ vbar, float* __restrict__ Zt,
                      float* __restrict__ acc) {
    __shared__ float red[256];
    int tid = threadIdx.x;
    int b = blockIdx.x;
    if (b >= DIN + 8) {                       // transpose path
        int j = b - (DIN + 8);
        Zt[j * MI + tid] = Z[tid * DIN + j];
        return;
    }
    if (b < DIN) {
        int j = b;
        int l = j >> 3, qq = j & 7;
        float lsv = ls[j];
        float ls2 = lsv * lsv;
        float s = 0.f;
        for (int n = tid; n < NH; n += 256) {
            float xv = Xm_v[(1 + n + l) * QD + qq];
            s += 1.0f / (2.0f * xv + ls2);
        }
        red[tid] = s;
        __syncthreads();
        for (int st = 128; st > 0; st >>= 1) {
            if (tid < st) red[tid] += red[tid + st];
            __syncthreads();
        }
        if (tid == 0) vbar[j] = red[0] * (1.0f / NH);
    } else {
        const float4* y4 = (const float4*)Y;
        float sy = 0.f;
        for (int i = (b - DIN) * 256 + tid; i < NH * DOUT / 4; i += 8 * 256) {
            float4 y = y4[i];
            sy += y.x * y.x + y.y * y.y + y.z * y.z + y.w * y.w;
        }
        red[tid] = sy;
        __syncthreads();
        for (int st = 128; st > 0; st >>= 1) {
            if (tid < st) red[tid] += red[tid + st];
            __syncthreads();
        }
        if (tid == 0) acc[b - DIN] = red[0];
    }
}

// ------ merged: psi1/Eg rows (n<2000) | Kuu+F rows (n>=2000) ----------------
__global__ void k_mainkuu(const float* __restrict__ Xm_m, const float* __restrict__ Xm_v,
                          const float* __restrict__ Zt, const float* __restrict__ Z,
                          const float* __restrict__ ls, const float* __restrict__ vbar,
                          const float* __restrict__ kvp,
                          float* __restrict__ psi1, float* __restrict__ Eg,
                          float* __restrict__ Kuu, float* __restrict__ F) {
    __shared__ float xm[DIN], h1[DIN], v2[DIN];
    __shared__ float red1[DIN], red2[DIN];
    __shared__ float sc[2];
    int tid = threadIdx.x;
    int n = blockIdx.x;
    if (n < NH) {
        if (tid < DIN) {
            int j = tid;
            int l = j >> 3, qq = j & 7;
            int row = 1 + n + l;                       // hankel(v[1:], Lt)
            float xmv = Xm_m[row * QD + qq];
            float xvv = Xm_v[row * QD + qq];
            float lsv = ls[j];
            float ls2 = lsv * lsv;
            float iv1 = 1.0f / (xvv + ls2);
            float iv2 = 1.0f / (2.0f * xvv + ls2);
            xm[j] = xmv; h1[j] = 0.5f * iv1; v2[j] = iv2;
            red1[j] = 0.5f * __logf(ls2 * iv1);
            red2[j] = 0.25f * __logf(ls2 * iv2) - 0.5f * xmv * xmv * iv2;
        }
        __syncthreads();
        if (tid == 0) {
            float a = 0.f, b = 0.f;
            for (int j = 0; j < DIN; ++j) { a += red1[j]; b += red2[j]; }
            sc[0] = a; sc[1] = b;
        }
        __syncthreads();
        float c1 = sc[0], c2h = sc[1];
        float e1h = 0.f, P = 0.f;
        #pragma unroll 8
        for (int j = 0; j < DIN; ++j) {
            float z = Zt[j * MI + tid];
            float d = z - xm[j];
            e1h += h1[j] * d * d;
            P += v2[j] * z * (0.25f * z - xm[j]);
        }
        float kv = kvp[0];
        psi1[n * MI + tid] = kv * __expf(c1 - e1h);
        Eg [n * MI + tid] = __expf(c2h - P);
    } else {
        int b = n - NH;
        if (tid < DIN) {
            float l = ls[tid];
            xm[tid] = 1.0f / (l * l);        // ils2
            h1[tid] = Z[b * DIN + tid];      // zb row
            v2[tid] = vbar[tid];
        }
        __syncthreads();
        float d2a = 0.f, c0 = 0.f;
        #pragma unroll 8
        for (int j = 0; j < DIN; ++j) {
            float za = Zt[j * MI + tid];
            float zb = h1[j];
            float d = za - zb;
            d2a += d * d * xm[j];
            c0 += v2[j] * za * zb;
        }
        float kv = kvp[0];
        int a = tid;
        Kuu[b * MI + a] = kv * __expf(-0.5f * d2a) + (a == b ? JITTER : 0.f);
        F  [b * MI + a] = kv * kv * __expf(-0.25f * d2a - 0.5f * c0);
    }
}

// ------ merged: split-K SYRK (bx < 16*nsplit) | Gpart (bx >= 16*nsplit) -----
__global__ void k_syrkG(const float* __restrict__ Eg, const float* __restrict__ psi1,
                        const float* __restrict__ Y,
                        float* __restrict__ Spart, float* __restrict__ Gpart,
                        int nsplit, int rowsPer) {
    __shared__ __align__(16) float As[16 * 64], Bs[16 * 64];
    int tid = threadIdx.x;
    int bx = blockIdx.x;
    if (bx < 16 * nsplit) {
        int tile = bx & 15, y = bx >> 4;
        int ta = tile & 3, tb = tile >> 2;
        int k0 = y * rowsPer;
        int tx = tid & 15, ty = tid >> 4;
        float acc[4][4] = {};
        for (int kk = k0; kk < k0 + rowsPer; kk += 16) {
            __syncthreads();
            for (int i = tid; i < 1024; i += 256) {
                int k = i >> 6, c = i & 63;
                As[k * 64 + c] = Eg[(kk + k) * MI + 64 * ta + c];
                Bs[k * 64 + c] = Eg[(kk + k) * MI + 64 * tb + c];
            }
            __syncthreads();
            #pragma unroll
            for (int k = 0; k < 16; ++k) {
                float4 a4 = *(const float4*)&As[k * 64 + 4 * tx];
                float4 b4 = *(const float4*)&Bs[k * 64 + 4 * ty];
                float a[4] = {a4.x, a4.y, a4.z, a4.w};
                float b[4] = {b4.x, b4.y, b4.z, b4.w};
                #pragma unroll
                for (int i = 0; i < 4; ++i)
                    #pragma unroll
                    for (int j = 0; j < 4; ++j)
                        acc[i][j] += a[i] * b[j];
            }
        }
        float* out = Spart + y * (MI * MI);
        #pragma unroll
        for (int i = 0; i < 4; ++i)
            #pragma unroll
            for (int j = 0; j < 4; ++j)
                out[(64 * ta + 4 * tx + i) * MI + 64 * tb + 4 * ty + j] = acc[i][j];
    } else {
        int gb = bx - 16 * nsplit;           // 0..79
        float* Ys = As;                       // reuse LDS
        int n0 = gb * 25;
        for (int i = tid; i < 25 * DOUT; i += 256) Ys[i] = Y[n0 * DOUT + i];
        __syncthreads();
        float acc[DOUT] = {};
        #pragma unroll
        for (int m = 0; m < 25; ++m) {
            float p = psi1[(n0 + m) * MI + tid];
            #pragma unroll
            for (int d = 0; d < DOUT; ++d) acc[d] += p * Ys[m * DOUT + d];
        }
        float4* out = (float4*)(Gpart + gb * (MI * DOUT) + tid * DOUT);
        out[0] = make_float4(acc[0], acc[1], acc[2], acc[3]);
        out[1] = make_float4(acc[4], acc[5], acc[6], acc[7]);
        out[2] = make_float4(acc[8], acc[9], acc[10], acc[11]);
        out[3] = make_float4(acc[12], acc[13], acc[14], acc[15]);
    }
}

// ------ merged: S/M2 assembly (bx<256) | Gsum (bx>=256) ---------------------
__global__ void k_psi2MG(const float* __restrict__ F, const float* __restrict__ Spart,
                         const float* __restrict__ Kuu, const float* __restrict__ Gpart,
                         float* __restrict__ S, float* __restrict__ M2,
                         float* __restrict__ G, int nsplit) {
    int tid = threadIdx.x;
    int bx = blockIdx.x;
    if (bx < 256) {
        int i = bx * 256 + tid;
        float s = 0.f;
        for (int y = 0; y < nsplit; ++y) s += Spart[y * (MI * MI) + i];
        float v = F[i] * s;
        S[i] = v;
        M2[i] = Kuu[i] + INV_SIGMA2 * v;
    } else {
        int gid = (bx - 256) * 256 + tid;
        float s = 0.f;
        for (int b = 0; b < 80; ++b) s += Gpart[b * (MI * DOUT) + gid];
        G[gid] = s;
    }
}

// ------- 64x64 diag: augmented [A|I], RANK-2, + fused panel TRSM ------------
__global__ void k_dchol(float* __restrict__ AK, float* __restrict__ AM,
                        float* __restrict__ LiK, float* __restrict__ LiM,
                        float* __restrict__ acc, int p) {
    float* A  = blockIdx.x ? AM : AK;
    float* Li = blockIdx.x ? LiM : LiK;
    const int c0 = 64 * p;
    __shared__ float colA[2][64], colB[2][64];
    __shared__ float rowEA[2][64], rowEB[2][64];
    __shared__ float isr[64];
    __shared__ float LsT[64 * 68];      // LsT[c*68+r] = Linv[r][c]
    __shared__ float As[64 * 68];       // As[k*68+r] = A21[r][k]
    int tid = threadIdx.x;              // 512
    int tx = tid & 15;
    int ty = tid >> 4;
    bool isA = ty < 16;
    int cb = isA ? 4 * ty : 4 * (ty - 16);
    float t[4][4];
    if (isA) {
        #pragma unroll
        for (int i = 0; i < 4; ++i)
            #pragma unroll
            for (int j = 0; j < 4; ++j)
                t[i][j] = A[(c0 + 4 * tx + i) * MI + c0 + cb + j];
    } else {
        #pragma unroll
        for (int i = 0; i < 4; ++i)
            #pragma unroll
            for (int j = 0; j < 4; ++j)
                t[i][j] = (4 * tx + i == cb + j) ? 1.f : 0.f;
    }
    if (isA && ty == 0) {
        #pragma unroll
        for (int i = 0; i < 4; ++i) {
            colA[0][4 * tx + i] = t[i][0];
            colB[0][4 * tx + i] = t[i][1];
        }
    }
    if (tid < 64) {
        rowEA[0][tid] = (tid == 0) ? 1.f : 0.f;
        rowEB[0][tid] = (tid == 1) ? 1.f : 0.f;
    }
    __syncthreads();
    float lgsum = 0.f;
    for (int s = 0; s < 32; ++s) {
        int pb = s & 1;
        int k0 = 2 * s, k1 = 2 * s + 1;
        float pk0 = colA[pb][k0];
        float ip0 = 1.0f / pk0;
        float m10 = colA[pb][k1] * ip0;
        float pk1 = colB[pb][k1] - m10 * colA[pb][k1];
        float ip1 = 1.0f / pk1;
        if (tid == 0) {
            isr[k0] = rsqrtf(pk0); isr[k1] = rsqrtf(pk1);
            lgsum += __logf(pk0) + __logf(pk1);
        }
        float a0[4], a1[4], b0[4], b1[4];
        #pragma unroll
        for (int i = 0; i < 4; ++i) {
            int r = 4 * tx + i;
            float cA = colA[pb][r], cB = colB[pb][r];
            a0[i] = (r > k0) ? cA * ip0 : 0.f;
            a1[i] = (r > k1) ? (cB - m10 * cA) * ip1 : 0.f;
        }
        if (isA) {
            #pragma unroll
            for (int j = 0; j < 4; ++j) {
                int c = cb + j;
                float cA = colA[pb][c], cB = colB[pb][c];
                b0[j] = (c > k0) ? cA : 0.f;
                b1[j] = (c > k1) ? (cB - m10 * cA) : 0.f;
            }
        } else {
            #pragma unroll
            for (int j = 0; j < 4; ++j) {
                float eA = rowEA[pb][cb + j], eB = rowEB[pb][cb + j];
                b0[j] = eA;
                b1[j] = eB - m10 * eA;
            }
        }
        #pragma unroll
        for (int i = 0; i < 4; ++i)
            #pragma unroll
            for (int j = 0; j < 4; ++j) {
                t[i][j] = fmaf(-a0[i], b0[j], t[i][j]);
                t[i][j] = fmaf(-a1[i], b1[j], t[i][j]);
            }
        if (s < 31) {
            int kn0 = k0 + 2;
            if (isA && ty == (kn0 >> 2)) {
                int j0 = kn0 & 3;
                #pragma unroll
                for (int jj = 0; jj < 4; ++jj) {
                    if (jj == j0) {
                        #pragma unroll
                        for (int i = 0; i < 4; ++i) colA[1 - pb][4 * tx + i] = t[i][jj];
                    }
                    if (jj == j0 + 1) {
                        #pragma unroll
                        for (int i = 0; i < 4; ++i) colB[1 - pb][4 * tx + i] = t[i][jj];
                    }
                }
            }
            if (!isA && tx == (kn0 >> 2)) {
                int i0 = kn0 & 3;
                #pragma unroll
                for (int ii = 0; ii < 4; ++ii) {
                    if (ii == i0) {
                        #pragma unroll
                        for (int j = 0; j < 4; ++j) rowEA[1 - pb][cb + j] = t[ii][j];
                    }
                    if (ii == i0 + 1) {
                        #pragma unroll
                        for (int j = 0; j < 4; ++j) rowEB[1 - pb][cb + j] = t[ii][j];
                    }
                }
            }
        }
        __syncthreads();
    }
    if (tid == 0) acc[8 + 4 * blockIdx.x + p] = lgsum;
    if (!isA) {
        #pragma unroll
        for (int i = 0; i < 4; ++i) {
            int r = 4 * tx + i;
            float sc = isr[r];
            #pragma unroll
            for (int j = 0; j < 4; ++j) {
                float v = t[i][j] * sc;
                Li[(c0 + r) * MI + c0 + cb + j] = v;
                LsT[(cb + j) * 68 + r] = v;
            }
        }
    }
    for (int jb = p + 1; jb < 4; ++jb)
        for (int q = tid; q < 4096; q += 512) {
            int rr = q >> 6, cc = q & 63;
            Li[(c0 + rr) * MI + 64 * jb + cc] = 0.f;
        }
    if (p < 3) {
        __syncthreads();
        for (int rb = 0; rb < 3 - p; ++rb) {
            int R0 = c0 + 64 + 64 * rb;
            for (int q = tid; q < 4096; q += 512) {
                int rr = q >> 6, k = q & 63;
                As[k * 68 + rr] = A[(R0 + rr) * MI + c0 + k];
            }
            __syncthreads();
            if (tid < 256) {
                int txc = tid & 15, tyc = tid >> 4;
                float acc4[4][4] = {};
                #pragma unroll 4
                for (int k = 0; k < 64; ++k) {
                    float4 a4 = *(const float4*)&As[k * 68 + 4 * txc];
                    float4 b4 = *(const float4*)&LsT[k * 68 + 4 * tyc];
                    float a[4] = {a4.x, a4.y, a4.z, a4.w};
                    float b[4] = {b4.x, b4.y, b4.z, b4.w};
                    #pragma unroll
                    for (int i = 0; i < 4; ++i)
                        #pragma unroll
                        for (int j = 0; j < 4; ++j)
                            acc4[i][j] += a[i] * b[j];
                }
                #pragma unroll
                for (int i = 0; i < 4; ++i)
                    #pragma unroll
                    for (int j = 0; j < 4; ++j)
                        A[(R0 + 4 * txc + i) * MI + c0 + 4 * tyc + j] = acc4[i][j];
            }
            __syncthreads();
        }
    }
}

// ---------------- trailing update: A22 -= Lp * Lp^T (64x64x64 tiles) --------
__global__ void k_cholu(float* __restrict__ AK, float* __restrict__ AM, int p) {
    float* A = blockIdx.y ? AM : AK;
    int t0 = 64 * (p + 1);
    int idx = blockIdx.x, ti = 0;
    while (idx > ti) { idx -= ti + 1; ti++; }
    int tj = idx;
    int R0 = t0 + 64 * ti, C0 = t0 + 64 * tj, K0 = 64 * p;
    __shared__ float As[64 * 68], Bs[64 * 68];
    int tid = threadIdx.x;
    int tx = tid & 15, ty = tid >> 4;
    for (int q = tid; q < 4096; q += 256) {
        int rr = q >> 6, k = q & 63;
        As[k * 68 + rr] = A[(R0 + rr) * MI + K0 + k];
        Bs[k * 68 + rr] = A[(C0 + rr) * MI + K0 + k];
    }
    __syncthreads();
    float acc[4][4] = {};
    #pragma unroll 4
    for (int k = 0; k < 64; ++k) {
        float4 a4 = *(const float4*)&As[k * 68 + 4 * tx];
        float4 b4 = *(const float4*)&Bs[k * 68 + 4 * ty];
        float a[4] = {a4.x, a4.y, a4.z, a4.w};
        float b[4] = {b4.x, b4.y, b4.z, b4.w};
        #pragma unroll
        for (int i = 0; i < 4; ++i)
            #pragma unroll
            for (int j = 0; j < 4; ++j)
                acc[i][j] += a[i] * b[j];
    }
    #pragma unroll
    for (int i = 0; i < 4; ++i)
        #pragma unroll
        for (int j = 0; j < 4; ++j) {
            int g = (R0 + 4 * tx + i) * MI + C0 + 4 * ty + j;
            A[g] -= acc[i][j];
        }
}

// ---- all off-diagonal Linv blocks of one column (in-block serial chain) ----
// r16/r18 lessons: pad LDS tiles to stride 68; keep this merged (single
// launch beats 3 launches + gaps on this harness).
__global__ void k_toff2(const float* __restrict__ LAK, const float* __restrict__ LAM,
                        float* __restrict__ LiK, float* __restrict__ LiM) {
    const float* LA = blockIdx.y ? LAM : LAK;
    float* Li = blockIdx.y ? LiM : LiK;
    int j = blockIdx.x;                  // 0..2
    __shared__ float Xs[3][64 * 68];
    __shared__ float As[64 * 68];
    __shared__ float T[64 * 68];
    int tid = threadIdx.x;
    int tx = tid & 15, ty = tid >> 4;
    // Xs[0] = Linv_jj (from dchol)
    for (int q = tid; q < 4096; q += 256) {
        int k = q >> 6, c = q & 63;
        Xs[0][k * 68 + c] = Li[(64 * j + k) * MI + 64 * j + c];
    }
    __syncthreads();
    for (int d = 1; d <= 3 - j; ++d) {
        int i = j + d;
        float acc[4][4] = {};
        for (int m = 0; m < d; ++m) {
            int kb = j + m;
            for (int q = tid; q < 4096; q += 256) {
                int rr = q >> 6, k = q & 63;
                As[k * 68 + rr] = LA[(64 * i + rr) * MI + 64 * kb + k];
            }
            __syncthreads();
            #pragma unroll 4
            for (int k = 0; k < 64; ++k) {
                float4 a4 = *(const float4*)&As[k * 68 + 4 * tx];
                float4 b4 = *(const float4*)&Xs[m][k * 68 + 4 * ty];
                float a[4] = {a4.x, a4.y, a4.z, a4.w};
                float b[4] = {b4.x, b4.y, b4.z, b4.w};
                #pragma unroll
                for (int i2 = 0; i2 < 4; ++i2)
                    #pragma unroll
                    for (int j2 = 0; j2 < 4; ++j2)
                        acc[i2][j2] += a[i2] * b[j2];
            }
            __syncthreads();              // As reused next m
        }
        // T[r][c] = acc ; As[k*68+r] = Linv_ii[r][k]
        #pragma unroll
        for (int i2 = 0; i2 < 4; ++i2)
            #pragma unroll
            for (int j2 = 0; j2 < 4; ++j2)
                T[(4 * tx + i2) * 68 + 4 * ty + j2] = acc[i2][j2];
        for (int q = tid; q < 4096; q += 256) {
            int rr = q >> 6, k = q & 63;
            As[k * 68 + rr] = Li[(64 * i + rr) * MI + 64 * i + k];
        }
        __syncthreads();
        float out[4][4] = {};
        #pragma unroll 4
        for (int k = 0; k < 64; ++k) {
            float4 a4 = *(const float4*)&As[k * 68 + 4 * tx];
            float4 b4 = *(const float4*)&T[k * 68 + 4 * ty];
            float a[4] = {a4.x, a4.y, a4.z, a4.w};
            float b[4] = {b4.x, b4.y, b4.z, b4.w};
            #pragma unroll
            for (int i2 = 0; i2 < 4; ++i2)
                #pragma unroll
                for (int j2 = 0; j2 < 4; ++j2)
                    out[i2][j2] += a[i2] * b[j2];
        }
        #pragma unroll
        for (int i2 = 0; i2 < 4; ++i2)
            #pragma unroll
            for (int j2 = 0; j2 < 4; ++j2) {
                float v = -out[i2][j2];
                Li[(64 * i + 4 * tx + i2) * MI + 64 * j + 4 * ty + j2] = v;
                Xs[d][(4 * tx + i2) * 68 + 4 * ty + j2] = v;
            }
        __syncthreads();                  // Xs[d], As, T settle before next d
    }
}

// -------- trace partials: Tpart[slot] = <Li_tile * S_slab, Li_tile> ---------
__global__ void k_trace(const float* __restrict__ Li, const float* __restrict__ S,
                        float* __restrict__ Tpart) {
    int R = 64 * (blockIdx.x >> 2), C = 64 * (blockIdx.x & 3);
    int k0 = 16 * blockIdx.y;
    int slot = blockIdx.y * 16 + blockIdx.x;
    if (C > R || k0 >= R + 64) {
        if (threadIdx.x == 0) Tpart[slot] = 0.f;
        return;
    }
    __shared__ __align__(16) float As[16 * 68], Bs[16 * 68];
    __shared__ float red[256];
    int tid = threadIdx.x;
    int tx = tid & 15, ty = tid >> 4;
    for (int q = tid; q < 1024; q += 256) {
        int rr = q >> 4, kk = q & 15;
        As[kk * 68 + rr] = Li[(R + rr) * MI + k0 + kk];
    }
    for (int q = tid; q < 1024; q += 256) {
        int kk = q >> 6, c = q & 63;
        Bs[kk * 68 + c] = S[(k0 + kk) * MI + C + c];
    }
    __syncthreads();
    float acc4[4][4] = {};
    #pragma unroll
    for (int k = 0; k < 16; ++k) {
        float4 a4 = *(const float4*)&As[k * 68 + 4 * tx];
        float4 b4 = *(const float4*)&Bs[k * 68 + 4 * ty];
        float a[4] = {a4.x, a4.y, a4.z, a4.w};
        float b[4] = {b4.x, b4.y, b4.z, b4.w};
        #pragma unroll
        for (int i = 0; i < 4; ++i)
            #pragma unroll
            for (int j = 0; j < 4; ++j)
                acc4[i][j] += a[i] * b[j];
    }
    float ts = 0.f;
    #pragma unroll
    for (int i = 0; i < 4; ++i)
        #pragma unroll
        for (int j = 0; j < 4; ++j)
            ts += acc4[i][j] * Li[(R + 4 * tx + i) * MI + C + 4 * ty + j];
    red[tid] = ts;
    __syncthreads();
    for (int st = 128; st > 0; st >>= 1) {
        if (tid < st) red[tid] += red[tid + st];
        __syncthreads();
    }
    if (tid == 0) Tpart[slot] = red[0];
}

// -------- w = LinvM*G ; sum Tpart + acc slots ; assemble bound ----------
__global__ void k_final(const float* __restrict__ LiM, const float* __restrict__ G,
                        const float* __restrict__ Tpart,
                        const float* __restrict__ accbuf, const float* __restrict__ kvp,
                        float* __restrict__ out) {
    __shared__ float Gs[MI * DOUT];
    __shared__ float red[256], redT[256];
    __shared__ float accs[16];
    int tid = threadIdx.x;
    for (int i = tid; i < MI * DOUT; i += 256) Gs[i] = G[i];
    redT[tid] = Tpart[tid];
    if (tid < 16) accs[tid] = accbuf[tid];
    __syncthreads();
    float w[DOUT] = {};
    const float4* lrow4 = (const float4*)(LiM + tid * MI);
    for (int k4 = 0; k4 < MI / 4; ++k4) {
        float4 l = lrow4[k4];
        const float* g0 = &Gs[(4 * k4) * DOUT];
        #pragma unroll
        for (int d = 0; d < DOUT; ++d)
            w[d] += l.x * g0[d] + l.y * g0[DOUT + d] + l.z * g0[2 * DOUT + d] + l.w * g0[3 * DOUT + d];
    }
    float c2 = 0.f;
    #pragma unroll
    for (int d = 0; d < DOUT; ++d) c2 += w[d] * w[d];
    red[tid] = c2;
    __syncthreads();
    for (int st = 128; st > 0; st >>= 1) {
        if (tid < st) { red[tid] += red[tid + st]; redT[tid] += redT[tid + st]; }
        __syncthreads();
    }
    if (tid == 0) {
        float kv = kvp[0];
        float sumY2 = 0.f, ldK = 0.f, ldM = 0.f;
        for (int i = 0; i < 8; ++i) sumY2 += accs[i];
        for (int i = 8; i < 12; ++i) ldK += accs[i];
        for (int i = 12; i < 16; ++i) ldM += accs[i];
        float trace = redT[0] * INV_SIGMA2;
        float logdetB = ldM - ldK;
        float bound = -0.5f * (float)(NH * DOUT) * __logf(6.28318530717959f * SIGMA2)
                      - 0.5f * INV_SIGMA2 * sumY2
                      - 0.5f * (float)DOUT * ((float)NH * kv * INV_SIGMA2 - trace)
                      - 0.5f * (float)DOUT * logdetB
                      + 0.5f * 1.0e6f * red[0];
        out[0] = bound;
    }
}

extern "C" void kernel_launch(void* const* d_in, const int* in_sizes, int n_in,
                              void* d_out, int out_size, void* d_ws, size_t ws_size,
                              hipStream_t stream) {
    (void)in_sizes; (void)n_in; (void)out_size;
    const float* Xm_m = (const float*)d_in[0];
    const float* Xm_v = (const float*)d_in[1];
    const float* Z    = (const float*)d_in[2];
    const float* Y    = (const float*)d_in[3];
    const float* kvp  = (const float*)d_in[4];
    const float* ls   = (const float*)d_in[5];
    float* out = (float*)d_out;
    float* W = (float*)d_ws;

    float* acc   = W;              // 16 slots
    float* Tpart = W + 16;         // 256
    float* G     = W + 272;        // 4096
    float* LinvK = W + 4368;       // 65536
    float* LinvM = W + 69904;      // 65536
    float* vbar  = W + 135440;     // 80
    float* psi1  = W + 135520;     // 512000
    float* Eg    = W + 647520;     // 512000
    float* Kuu   = W + 1159520;    // 65536
    float* M2    = W + 1225056;    // 65536
    float* S     = W + 1290592;    // 65536
    float* F     = W + 1356128;    // 65536
    float* Zt    = W + 1421664;    // 20480
    float* Spart = W + 1442144;    // nsplit*65536
    // Gpart follows Spart: 80*4096 floats

    int nsplit = (ws_size >= (size_t)(1442144 + 25 * 65536 + 80 * 4096) * 4) ? 25 : 5;
    int rowsPer = NH / nsplit;
    float* Gpart = Spart + (size_t)nsplit * 65536;

    k_pre<<<DIN + 8 + DIN, 256, 0, stream>>>(Xm_v, Y, Z, ls, vbar, Zt, acc);
    k_mainkuu<<<NH + MI, 256, 0, stream>>>(Xm_m, Xm_v, Zt, Z, ls, vbar, kvp,
                                           psi1, Eg, Kuu, F);
    k_syrkG<<<16 * nsplit + 80, 256, 0, stream>>>(Eg, psi1, Y, Spart, Gpart,
                                                  nsplit, rowsPer);
    k_psi2MG<<<272, 256, 0, stream>>>(F, Spart, Kuu, Gpart, S, M2, G, nsplit);

    // batched blocked Cholesky (rank-2 augmented diag + fused TRSM) of {Kuu, M2}
    for (int p = 0; p < 4; ++p) {
        k_dchol<<<2, 512, 0, stream>>>(Kuu, M2, LinvK, LinvM, acc, p);
        if (p < 3) {
            int nt = 3 - p;
            k_cholu<<<dim3(nt * (nt + 1) / 2, 2), 256, 0, stream>>>(Kuu, M2, p);
        }
    }
    // off-diagonal Linv blocks: one launch, per-column serial chain in-block
    k_toff2<<<dim3(3, 2), 256, 0, stream>>>(Kuu, M2, LinvK, LinvM);

    k_trace<<<dim3(16, 16), 256, 0, stream>>>(LinvK, S, Tpart);
    k_final<<<1, 256, 0, stream>>>(LinvM, G, Tpart, acc, kvp, out);
}

// Round 20
// 300.613 us; speedup vs baseline: 1.1085x; 1.0105x over previous
//
#include <hip/hip_runtime.h>
#include <math.h>

// Problem constants (from setup_inputs: N_data=2000, Lt=10, Q=8, M=256, D=16)
#define NH   2000     // Hankel rows == Y rows
#define QD   8        // latent dim Q
#define DIN  80       // Lt*Q
#define MI   256      // inducing points
#define DOUT 16       // output dim D
#define SIGMA2     1e-3f
#define INV_SIGMA2 1000.0f
#define JITTER     1e-4f

// HARD-WON NOTES (rounds 1-19):
//  - per-thread arrays indexed dynamically -> scratch (4 ms).
//  - LARGE (64-float) register tiles across barriered loops spill; 4x4 cells
//    do NOT spill even across barriered serial loops.
//  - factorization serial loops cost ~1.2k cy/step; the lever is the NUMBER
//    of steps: r9 augmented [A|I] (128->64), r13 rank-2 (64->32 barriers).
//  - latency chains: single-wg kernels with serial load loops (r5 k_prep).
//  - parallelism-starved kernels: split-K until >= 1.5 blocks/CU.
//  - DEVICE ATOMICS ARE EXPENSIVE (r12): partial buffers + plain stores.
//  - r10 bug: LDS staging with `if (tid < N)` when N > blockDim -> poison.
//  - workspace is NOT zeroed (0xAA poison): every buffer fully written.
//  - r15: Z (80 KB) is cache-resident; coalescing was neutral.
//  - r16: stride-64 LDS tiles = 16-way conflicts; pad to 68.
//  - r18 A/B: a serialized launch gap costs ~10 us on this harness; merging
//    a dependency chain into ONE kernel wins even if the merged kernel is
//    individually 2x slower (306 vs 333). Keep toff2 merged.
//  - r19: single-block serial GEMM chains at 4 waves leave the LDS pipe
//    half-idle (~5 us/round vs 1.7 ideal) -> widen to 8 waves (512 thr).

// acc layout: [0..7] sum(Y^2) partials, [8..11] logdet-K, [12..15] logdet-M

// ------ merged: vbar (b<80) | sum(Y^2) (80<=b<88) | Zt transpose (b>=88) ----
__global__ void k_pre(const float* __restrict__ Xm_v, const float* __restrict__ Y,
                      const float* __restrict__ Z, const float* __restrict__ ls,
                      float* __restrict__ vbar, float* __restrict__ Zt,
                      float* __restrict__ acc) {
    __shared__ float red[256];
    int tid = threadIdx.x;
    int b = blockIdx.x;
    if (b >= DIN + 8) {                       // transpose path
        int j = b - (DIN + 8);
        Zt[j * MI + tid] = Z[tid * DIN + j];
        return;
    }
    if (b < DIN) {
        int j = b;
        int l = j >> 3, qq = j & 7;
        float lsv = ls[j];
        float ls2 = lsv * lsv;
        float s = 0.f;
        for (int n = tid; n < NH; n += 256) {
            float xv = Xm_v[(1 + n + l) * QD + qq];
            s += 1.0f / (2.0f * xv + ls2);
        }
        red[tid] = s;
        __syncthreads();
        for (int st = 128; st > 0; st >>= 1) {
            if (tid < st) red[tid] += red[tid + st];
            __syncthreads();
        }
        if (tid == 0) vbar[j] = red[0] * (1.0f / NH);
    } else {
        const float4* y4 = (const float4*)Y;
        float sy = 0.f;
        for (int i = (b - DIN) * 256 + tid; i < NH * DOUT / 4; i += 8 * 256) {
            float4 y = y4[i];
            sy += y.x * y.x + y.y * y.y + y.z * y.z + y.w * y.w;
        }
        red[tid] = sy;
        __syncthreads();
        for (int st = 128; st > 0; st >>= 1) {
            if (tid < st) red[tid] += red[tid + st];
            __syncthreads();
        }
        if (tid == 0) acc[b - DIN] = red[0];
    }
}

// ------ merged: psi1/Eg rows (n<2000) | Kuu+F rows (n>=2000) ----------------
__global__ void k_mainkuu(const float* __restrict__ Xm_m, const float* __restrict__ Xm_v,
                          const float* __restrict__ Zt, const float* __restrict__ Z,
                          const float* __restrict__ ls, const float* __restrict__ vbar,
                          const float* __restrict__ kvp,
                          float* __restrict__ psi1, float* __restrict__ Eg,
                          float* __restrict__ Kuu, float* __restrict__ F) {
    __shared__ float xm[DIN], h1[DIN], v2[DIN];
    __shared__ float red1[DIN], red2[DIN];
    __shared__ float sc[2];
    int tid = threadIdx.x;
    int n = blockIdx.x;
    if (n < NH) {
        if (tid < DIN) {
            int j = tid;
            int l = j >> 3, qq = j & 7;
            int row = 1 + n + l;                       // hankel(v[1:], Lt)
            float xmv = Xm_m[row * QD + qq];
            float xvv = Xm_v[row * QD + qq];
            float lsv = ls[j];
            float ls2 = lsv * lsv;
            float iv1 = 1.0f / (xvv + ls2);
            float iv2 = 1.0f / (2.0f * xvv + ls2);
            xm[j] = xmv; h1[j] = 0.5f * iv1; v2[j] = iv2;
            red1[j] = 0.5f * __logf(ls2 * iv1);
            red2[j] = 0.25f * __logf(ls2 * iv2) - 0.5f * xmv * xmv * iv2;
        }
        __syncthreads();
        if (tid == 0) {
            float a = 0.f, b = 0.f;
            for (int j = 0; j < DIN; ++j) { a += red1[j]; b += red2[j]; }
            sc[0] = a; sc[1] = b;
        }
        __syncthreads();
        float c1 = sc[0], c2h = sc[1];
        float e1h = 0.f, P = 0.f;
        #pragma unroll 8
        for (int j = 0; j < DIN; ++j) {
            float z = Zt[j * MI + tid];
            float d = z - xm[j];
            e1h += h1[j] * d * d;
            P += v2[j] * z * (0.25f * z - xm[j]);
        }
        float kv = kvp[0];
        psi1[n * MI + tid] = kv * __expf(c1 - e1h);
        Eg [n * MI + tid] = __expf(c2h - P);
    } else {
        int b = n - NH;
        if (tid < DIN) {
            float l = ls[tid];
            xm[tid] = 1.0f / (l * l);        // ils2
            h1[tid] = Z[b * DIN + tid];      // zb row
            v2[tid] = vbar[tid];
        }
        __syncthreads();
        float d2a = 0.f, c0 = 0.f;
        #pragma unroll 8
        for (int j = 0; j < DIN; ++j) {
            float za = Zt[j * MI + tid];
            float zb = h1[j];
            float d = za - zb;
            d2a += d * d * xm[j];
            c0 += v2[j] * za * zb;
        }
        float kv = kvp[0];
        int a = tid;
        Kuu[b * MI + a] = kv * __expf(-0.5f * d2a) + (a == b ? JITTER : 0.f);
        F  [b * MI + a] = kv * kv * __expf(-0.25f * d2a - 0.5f * c0);
    }
}

// ------ merged: split-K SYRK (bx < 16*nsplit) | Gpart (bx >= 16*nsplit) -----
__global__ void k_syrkG(const float* __restrict__ Eg, const float* __restrict__ psi1,
                        const float* __restrict__ Y,
                        float* __restrict__ Spart, float* __restrict__ Gpart,
                        int nsplit, int rowsPer) {
    __shared__ __align__(16) float As[16 * 64], Bs[16 * 64];
    int tid = threadIdx.x;
    int bx = blockIdx.x;
    if (bx < 16 * nsplit) {
        int tile = bx & 15, y = bx >> 4;
        int ta = tile & 3, tb = tile >> 2;
        int k0 = y * rowsPer;
        int tx = tid & 15, ty = tid >> 4;
        float acc[4][4] = {};
        for (int kk = k0; kk < k0 + rowsPer; kk += 16) {
            __syncthreads();
            for (int i = tid; i < 1024; i += 256) {
                int k = i >> 6, c = i & 63;
                As[k * 64 + c] = Eg[(kk + k) * MI + 64 * ta + c];
                Bs[k * 64 + c] = Eg[(kk + k) * MI + 64 * tb + c];
            }
            __syncthreads();
            #pragma unroll
            for (int k = 0; k < 16; ++k) {
                float4 a4 = *(const float4*)&As[k * 64 + 4 * tx];
                float4 b4 = *(const float4*)&Bs[k * 64 + 4 * ty];
                float a[4] = {a4.x, a4.y, a4.z, a4.w};
                float b[4] = {b4.x, b4.y, b4.z, b4.w};
                #pragma unroll
                for (int i = 0; i < 4; ++i)
                    #pragma unroll
                    for (int j = 0; j < 4; ++j)
                        acc[i][j] += a[i] * b[j];
            }
        }
        float* out = Spart + y * (MI * MI);
        #pragma unroll
        for (int i = 0; i < 4; ++i)
            #pragma unroll
            for (int j = 0; j < 4; ++j)
                out[(64 * ta + 4 * tx + i) * MI + 64 * tb + 4 * ty + j] = acc[i][j];
    } else {
        int gb = bx - 16 * nsplit;           // 0..79
        float* Ys = As;                       // reuse LDS
        int n0 = gb * 25;
        for (int i = tid; i < 25 * DOUT; i += 256) Ys[i] = Y[n0 * DOUT + i];
        __syncthreads();
        float acc[DOUT] = {};
        #pragma unroll
        for (int m = 0; m < 25; ++m) {
            float p = psi1[(n0 + m) * MI + tid];
            #pragma unroll
            for (int d = 0; d < DOUT; ++d) acc[d] += p * Ys[m * DOUT + d];
        }
        float4* out = (float4*)(Gpart + gb * (MI * DOUT) + tid * DOUT);
        out[0] = make_float4(acc[0], acc[1], acc[2], acc[3]);
        out[1] = make_float4(acc[4], acc[5], acc[6], acc[7]);
        out[2] = make_float4(acc[8], acc[9], acc[10], acc[11]);
        out[3] = make_float4(acc[12], acc[13], acc[14], acc[15]);
    }
}

// ------ merged: S/M2 assembly (bx<256) | Gsum (bx>=256) ---------------------
__global__ void k_psi2MG(const float* __restrict__ F, const float* __restrict__ Spart,
                         const float* __restrict__ Kuu, const float* __restrict__ Gpart,
                         float* __restrict__ S, float* __restrict__ M2,
                         float* __restrict__ G, int nsplit) {
    int tid = threadIdx.x;
    int bx = blockIdx.x;
    if (bx < 256) {
        int i = bx * 256 + tid;
        float s = 0.f;
        for (int y = 0; y < nsplit; ++y) s += Spart[y * (MI * MI) + i];
        float v = F[i] * s;
        S[i] = v;
        M2[i] = Kuu[i] + INV_SIGMA2 * v;
    } else {
        int gid = (bx - 256) * 256 + tid;
        float s = 0.f;
        for (int b = 0; b < 80; ++b) s += Gpart[b * (MI * DOUT) + gid];
        G[gid] = s;
    }
}

// ------- 64x64 diag: augmented [A|I], RANK-2, + fused panel TRSM ------------
__global__ void k_dchol(float* __restrict__ AK, float* __restrict__ AM,
                        float* __restrict__ LiK, float* __restrict__ LiM,
                        float* __restrict__ acc, int p) {
    float* A  = blockIdx.x ? AM : AK;
    float* Li = blockIdx.x ? LiM : LiK;
    const int c0 = 64 * p;
    __shared__ float colA[2][64], colB[2][64];
    __shared__ float rowEA[2][64], rowEB[2][64];
    __shared__ float isr[64];
    __shared__ float LsT[64 * 68];      // LsT[c*68+r] = Linv[r][c]
    __shared__ float As[64 * 68];       // As[k*68+r] = A21[r][k]
    int tid = threadIdx.x;              // 512
    int tx = tid & 15;
    int ty = tid >> 4;
    bool isA = ty < 16;
    int cb = isA ? 4 * ty : 4 * (ty - 16);
    float t[4][4];
    if (isA) {
        #pragma unroll
        for (int i = 0; i < 4; ++i)
            #pragma unroll
            for (int j = 0; j < 4; ++j)
                t[i][j] = A[(c0 + 4 * tx + i) * MI + c0 + cb + j];
    } else {
        #pragma unroll
        for (int i = 0; i < 4; ++i)
            #pragma unroll
            for (int j = 0; j < 4; ++j)
                t[i][j] = (4 * tx + i == cb + j) ? 1.f : 0.f;
    }
    if (isA && ty == 0) {
        #pragma unroll
        for (int i = 0; i < 4; ++i) {
            colA[0][4 * tx + i] = t[i][0];
            colB[0][4 * tx + i] = t[i][1];
        }
    }
    if (tid < 64) {
        rowEA[0][tid] = (tid == 0) ? 1.f : 0.f;
        rowEB[0][tid] = (tid == 1) ? 1.f : 0.f;
    }
    __syncthreads();
    float lgsum = 0.f;
    for (int s = 0; s < 32; ++s) {
        int pb = s & 1;
        int k0 = 2 * s, k1 = 2 * s + 1;
        float pk0 = colA[pb][k0];
        float ip0 = 1.0f / pk0;
        float m10 = colA[pb][k1] * ip0;
        float pk1 = colB[pb][k1] - m10 * colA[pb][k1];
        float ip1 = 1.0f / pk1;
        if (tid == 0) {
            isr[k0] = rsqrtf(pk0); isr[k1] = rsqrtf(pk1);
            lgsum += __logf(pk0) + __logf(pk1);
        }
        float a0[4], a1[4], b0[4], b1[4];
        #pragma unroll
        for (int i = 0; i < 4; ++i) {
            int r = 4 * tx + i;
            float cA = colA[pb][r], cB = colB[pb][r];
            a0[i] = (r > k0) ? cA * ip0 : 0.f;
            a1[i] = (r > k1) ? (cB - m10 * cA) * ip1 : 0.f;
        }
        if (isA) {
            #pragma unroll
            for (int j = 0; j < 4; ++j) {
                int c = cb + j;
                float cA = colA[pb][c], cB = colB[pb][c];
                b0[j] = (c > k0) ? cA : 0.f;
                b1[j] = (c > k1) ? (cB - m10 * cA) : 0.f;
            }
        } else {
            #pragma unroll
            for (int j = 0; j < 4; ++j) {
                float eA = rowEA[pb][cb + j], eB = rowEB[pb][cb + j];
                b0[j] = eA;
                b1[j] = eB - m10 * eA;
            }
        }
        #pragma unroll
        for (int i = 0; i < 4; ++i)
            #pragma unroll
            for (int j = 0; j < 4; ++j) {
                t[i][j] = fmaf(-a0[i], b0[j], t[i][j]);
                t[i][j] = fmaf(-a1[i], b1[j], t[i][j]);
            }
        if (s < 31) {
            int kn0 = k0 + 2;
            if (isA && ty == (kn0 >> 2)) {
                int j0 = kn0 & 3;
                #pragma unroll
                for (int jj = 0; jj < 4; ++jj) {
                    if (jj == j0) {
                        #pragma unroll
                        for (int i = 0; i < 4; ++i) colA[1 - pb][4 * tx + i] = t[i][jj];
                    }
                    if (jj == j0 + 1) {
                        #pragma unroll
                        for (int i = 0; i < 4; ++i) colB[1 - pb][4 * tx + i] = t[i][jj];
                    }
                }
            }
            if (!isA && tx == (kn0 >> 2)) {
                int i0 = kn0 & 3;
                #pragma unroll
                for (int ii = 0; ii < 4; ++ii) {
                    if (ii == i0) {
                        #pragma unroll
                        for (int j = 0; j < 4; ++j) rowEA[1 - pb][cb + j] = t[ii][j];
                    }
                    if (ii == i0 + 1) {
                        #pragma unroll
                        for (int j = 0; j < 4; ++j) rowEB[1 - pb][cb + j] = t[ii][j];
                    }
                }
            }
        }
        __syncthreads();
    }
    if (tid == 0) acc[8 + 4 * blockIdx.x + p] = lgsum;
    if (!isA) {
        #pragma unroll
        for (int i = 0; i < 4; ++i) {
            int r = 4 * tx + i;
            float sc = isr[r];
            #pragma unroll
            for (int j = 0; j < 4; ++j) {
                float v = t[i][j] * sc;
                Li[(c0 + r) * MI + c0 + cb + j] = v;
                LsT[(cb + j) * 68 + r] = v;
            }
        }
    }
    for (int jb = p + 1; jb < 4; ++jb)
        for (int q = tid; q < 4096; q += 512) {
            int rr = q >> 6, cc = q & 63;
            Li[(c0 + rr) * MI + 64 * jb + cc] = 0.f;
        }
    if (p < 3) {
        __syncthreads();
        for (int rb = 0; rb < 3 - p; ++rb) {
            int R0 = c0 + 64 + 64 * rb;
            for (int q = tid; q < 4096; q += 512) {
                int rr = q >> 6, k = q & 63;
                As[k * 68 + rr] = A[(R0 + rr) * MI + c0 + k];
            }
            __syncthreads();
            if (tid < 256) {
                int txc = tid & 15, tyc = tid >> 4;
                float acc4[4][4] = {};
                #pragma unroll 4
                for (int k = 0; k < 64; ++k) {
                    float4 a4 = *(const float4*)&As[k * 68 + 4 * txc];
                    float4 b4 = *(const float4*)&LsT[k * 68 + 4 * tyc];
                    float a[4] = {a4.x, a4.y, a4.z, a4.w};
                    float b[4] = {b4.x, b4.y, b4.z, b4.w};
                    #pragma unroll
                    for (int i = 0; i < 4; ++i)
                        #pragma unroll
                        for (int j = 0; j < 4; ++j)
                            acc4[i][j] += a[i] * b[j];
                }
                #pragma unroll
                for (int i = 0; i < 4; ++i)
                    #pragma unroll
                    for (int j = 0; j < 4; ++j)
                        A[(R0 + 4 * txc + i) * MI + c0 + 4 * tyc + j] = acc4[i][j];
            }
            __syncthreads();
        }
    }
}

// ---------------- trailing update: A22 -= Lp * Lp^T (64x64x64 tiles) --------
__global__ void k_cholu(float* __restrict__ AK, float* __restrict__ AM, int p) {
    float* A = blockIdx.y ? AM : AK;
    int t0 = 64 * (p + 1);
    int idx = blockIdx.x, ti = 0;
    while (idx > ti) { idx -= ti + 1; ti++; }
    int tj = idx;
    int R0 = t0 + 64 * ti, C0 = t0 + 64 * tj, K0 = 64 * p;
    __shared__ float As[64 * 68], Bs[64 * 68];
    int tid = threadIdx.x;
    int tx = tid & 15, ty = tid >> 4;
    for (int q = tid; q < 4096; q += 256) {
        int rr = q >> 6, k = q & 63;
        As[k * 68 + rr] = A[(R0 + rr) * MI + K0 + k];
        Bs[k * 68 + rr] = A[(C0 + rr) * MI + K0 + k];
    }
    __syncthreads();
    float acc[4][4] = {};
    #pragma unroll 4
    for (int k = 0; k < 64; ++k) {
        float4 a4 = *(const float4*)&As[k * 68 + 4 * tx];
        float4 b4 = *(const float4*)&Bs[k * 68 + 4 * ty];
        float a[4] = {a4.x, a4.y, a4.z, a4.w};
        float b[4] = {b4.x, b4.y, b4.z, b4.w};
        #pragma unroll
        for (int i = 0; i < 4; ++i)
            #pragma unroll
            for (int j = 0; j < 4; ++j)
                acc[i][j] += a[i] * b[j];
    }
    #pragma unroll
    for (int i = 0; i < 4; ++i)
        #pragma unroll
        for (int j = 0; j < 4; ++j) {
            int g = (R0 + 4 * tx + i) * MI + C0 + 4 * ty + j;
            A[g] -= acc[i][j];
        }
}

// ---- all off-diagonal Linv blocks of one column (in-block serial chain) ----
// 512 threads (8 waves: hide staging latency, saturate LDS pipe); 4x2 cells.
// Stride-68 padded LDS throughout.
__global__ void k_toff2(const float* __restrict__ LAK, const float* __restrict__ LAM,
                        float* __restrict__ LiK, float* __restrict__ LiM) {
    const float* LA = blockIdx.y ? LAM : LAK;
    float* Li = blockIdx.y ? LiM : LiK;
    int j = blockIdx.x;                  // 0..2
    __shared__ float Xs[3][64 * 68];
    __shared__ float As[64 * 68];
    __shared__ float T[64 * 68];
    int tid = threadIdx.x;               // 512
    int tx = tid & 15;                   // rows 4tx..4tx+3
    int ty = tid >> 4;                   // 0..31, cols 2ty..2ty+1
    // Xs[0] = Linv_jj (from dchol)
    for (int q = tid; q < 4096; q += 512) {
        int k = q >> 6, c = q & 63;
        Xs[0][k * 68 + c] = Li[(64 * j + k) * MI + 64 * j + c];
    }
    __syncthreads();
    for (int d = 1; d <= 3 - j; ++d) {
        int i = j + d;
        float acc[4][2] = {};
        for (int m = 0; m < d; ++m) {
            int kb = j + m;
            for (int q = tid; q < 4096; q += 512) {
                int rr = q >> 6, k = q & 63;
                As[k * 68 + rr] = LA[(64 * i + rr) * MI + 64 * kb + k];
            }
            __syncthreads();
            #pragma unroll 4
            for (int k = 0; k < 64; ++k) {
                float4 a4 = *(const float4*)&As[k * 68 + 4 * tx];
                float2 b2 = *(const float2*)&Xs[m][k * 68 + 2 * ty];
                float a[4] = {a4.x, a4.y, a4.z, a4.w};
                float b[2] = {b2.x, b2.y};
                #pragma unroll
                for (int i2 = 0; i2 < 4; ++i2)
                    #pragma unroll
                    for (int j2 = 0; j2 < 2; ++j2)
                        acc[i2][j2] += a[i2] * b[j2];
            }
            __syncthreads();              // As reused next m
        }
        // T[r][c] = acc ; As[k*68+r] = Linv_ii[r][k]
        #pragma unroll
        for (int i2 = 0; i2 < 4; ++i2)
            #pragma unroll
            for (int j2 = 0; j2 < 2; ++j2)
                T[(4 * tx + i2) * 68 + 2 * ty + j2] = acc[i2][j2];
        for (int q = tid; q < 4096; q += 512) {
            int rr = q >> 6, k = q & 63;
            As[k * 68 + rr] = Li[(64 * i + rr) * MI + 64 * i + k];
        }
        __syncthreads();
        float out[4][2] = {};
        #pragma unroll 4
        for (int k = 0; k < 64; ++k) {
            float4 a4 = *(const float4*)&As[k * 68 + 4 * tx];
            float2 b2 = *(const float2*)&T[k * 68 + 2 * ty];
            float a[4] = {a4.x, a4.y, a4.z, a4.w};
            float b[2] = {b2.x, b2.y};
            #pragma unroll
            for (int i2 = 0; i2 < 4; ++i2)
                #pragma unroll
                for (int j2 = 0; j2 < 2; ++j2)
                    out[i2][j2] += a[i2] * b[j2];
        }
        #pragma unroll
        for (int i2 = 0; i2 < 4; ++i2)
            #pragma unroll
            for (int j2 = 0; j2 < 2; ++j2) {
                float v = -out[i2][j2];
                Li[(64 * i + 4 * tx + i2) * MI + 64 * j + 2 * ty + j2] = v;
                Xs[d][(4 * tx + i2) * 68 + 2 * ty + j2] = v;
            }
        __syncthreads();                  // Xs[d], As, T settle before next d
    }
}

// -------- trace partials: Tpart[slot] = <Li_tile * S_slab, Li_tile> ---------
__global__ void k_trace(const float* __restrict__ Li, const float* __restrict__ S,
                        float* __restrict__ Tpart) {
    int R = 64 * (blockIdx.x >> 2), C = 64 * (blockIdx.x & 3);
    int k0 = 16 * blockIdx.y;
    int slot = blockIdx.y * 16 + blockIdx.x;
    if (C > R || k0 >= R + 64) {
        if (threadIdx.x == 0) Tpart[slot] = 0.f;
        return;
    }
    __shared__ __align__(16) float As[16 * 68], Bs[16 * 68];
    __shared__ float red[256];
    int tid = threadIdx.x;
    int tx = tid & 15, ty = tid >> 4;
    for (int q = tid; q < 1024; q += 256) {
        int rr = q >> 4, kk = q & 15;
        As[kk * 68 + rr] = Li[(R + rr) * MI + k0 + kk];
    }
    for (int q = tid; q < 1024; q += 256) {
        int kk = q >> 6, c = q & 63;
        Bs[kk * 68 + c] = S[(k0 + kk) * MI + C + c];
    }
    __syncthreads();
    float acc4[4][4] = {};
    #pragma unroll
    for (int k = 0; k < 16; ++k) {
        float4 a4 = *(const float4*)&As[k * 68 + 4 * tx];
        float4 b4 = *(const float4*)&Bs[k * 68 + 4 * ty];
        float a[4] = {a4.x, a4.y, a4.z, a4.w};
        float b[4] = {b4.x, b4.y, b4.z, b4.w};
        #pragma unroll
        for (int i = 0; i < 4; ++i)
            #pragma unroll
            for (int j = 0; j < 4; ++j)
                acc4[i][j] += a[i] * b[j];
    }
    float ts = 0.f;
    #pragma unroll
    for (int i = 0; i < 4; ++i)
        #pragma unroll
        for (int j = 0; j < 4; ++j)
            ts += acc4[i][j] * Li[(R + 4 * tx + i) * MI + C + 4 * ty + j];
    red[tid] = ts;
    __syncthreads();
    for (int st = 128; st > 0; st >>= 1) {
        if (tid < st) red[tid] += red[tid + st];
        __syncthreads();
    }
    if (tid == 0) Tpart[slot] = red[0];
}

// -------- w = LinvM*G ; sum Tpart + acc slots ; assemble bound ----------
__global__ void k_final(const float* __restrict__ LiM, const float* __restrict__ G,
                        const float* __restrict__ Tpart,
                        const float* __restrict__ accbuf, const float* __restrict__ kvp,
                        float* __restrict__ out) {
    __shared__ float Gs[MI * DOUT];
    __shared__ float red[256], redT[256];
    __shared__ float accs[16];
    int tid = threadIdx.x;
    for (int i = tid; i < MI * DOUT; i += 256) Gs[i] = G[i];
    redT[tid] = Tpart[tid];
    if (tid < 16) accs[tid] = accbuf[tid];
    __syncthreads();
    float w[DOUT] = {};
    const float4* lrow4 = (const float4*)(LiM + tid * MI);
    for (int k4 = 0; k4 < MI / 4; ++k4) {
        float4 l = lrow4[k4];
        const float* g0 = &Gs[(4 * k4) * DOUT];
        #pragma unroll
        for (int d = 0; d < DOUT; ++d)
            w[d] += l.x * g0[d] + l.y * g0[DOUT + d] + l.z * g0[2 * DOUT + d] + l.w * g0[3 * DOUT + d];
    }
    float c2 = 0.f;
    #pragma unroll
    for (int d = 0; d < DOUT; ++d) c2 += w[d] * w[d];
    red[tid] = c2;
    __syncthreads();
    for (int st = 128; st > 0; st >>= 1) {
        if (tid < st) { red[tid] += red[tid + st]; redT[tid] += redT[tid + st]; }
        __syncthreads();
    }
    if (tid == 0) {
        float kv = kvp[0];
        float sumY2 = 0.f, ldK = 0.f, ldM = 0.f;
        for (int i = 0; i < 8; ++i) sumY2 += accs[i];
        for (int i = 8; i < 12; ++i) ldK += accs[i];
        for (int i = 12; i < 16; ++i) ldM += accs[i];
        float trace = redT[0] * INV_SIGMA2;
        float logdetB = ldM - ldK;
        float bound = -0.5f * (float)(NH * DOUT) * __logf(6.28318530717959f * SIGMA2)
                      - 0.5f * INV_SIGMA2 * sumY2
                      - 0.5f * (float)DOUT * ((float)NH * kv * INV_SIGMA2 - trace)
                      - 0.5f * (float)DOUT * logdetB
                      + 0.5f * 1.0e6f * red[0];
        out[0] = bound;
    }
}

extern "C" void kernel_launch(void* const* d_in, const int* in_sizes, int n_in,
                              void* d_out, int out_size, void* d_ws, size_t ws_size,
                              hipStream_t stream) {
    (void)in_sizes; (void)n_in; (void)out_size;
    const float* Xm_m = (const float*)d_in[0];
    const float* Xm_v = (const float*)d_in[1];
    const float* Z    = (const float*)d_in[2];
    const float* Y    = (const float*)d_in[3];
    const float* kvp  = (const float*)d_in[4];
    const float* ls   = (const float*)d_in[5];
    float* out = (float*)d_out;
    float* W = (float*)d_ws;

    float* acc   = W;              // 16 slots
    float* Tpart = W + 16;         // 256
    float* G     = W + 272;        // 4096
    float* LinvK = W + 4368;       // 65536
    float* LinvM = W + 69904;      // 65536
    float* vbar  = W + 135440;     // 80
    float* psi1  = W + 135520;     // 512000
    float* Eg    = W + 647520;     // 512000
    float* Kuu   = W + 1159520;    // 65536
    float* M2    = W + 1225056;    // 65536
    float* S     = W + 1290592;    // 65536
    float* F     = W + 1356128;    // 65536
    float* Zt    = W + 1421664;    // 20480
    float* Spart = W + 1442144;    // nsplit*65536
    // Gpart follows Spart: 80*4096 floats

    int nsplit = (ws_size >= (size_t)(1442144 + 25 * 65536 + 80 * 4096) * 4) ? 25 : 5;
    int rowsPer = NH / nsplit;
    float* Gpart = Spart + (size_t)nsplit * 65536;

    k_pre<<<DIN + 8 + DIN, 256, 0, stream>>>(Xm_v, Y, Z, ls, vbar, Zt, acc);
    k_mainkuu<<<NH + MI, 256, 0, stream>>>(Xm_m, Xm_v, Zt, Z, ls, vbar, kvp,
                                           psi1, Eg, Kuu, F);
    k_syrkG<<<16 * nsplit + 80, 256, 0, stream>>>(Eg, psi1, Y, Spart, Gpart,
                                                  nsplit, rowsPer);
    k_psi2MG<<<272, 256, 0, stream>>>(F, Spart, Kuu, Gpart, S, M2, G, nsplit);

    // batched blocked Cholesky (rank-2 augmented diag + fused TRSM) of {Kuu, M2}
    for (int p = 0; p < 4; ++p) {
        k_dchol<<<2, 512, 0, stream>>>(Kuu, M2, LinvK, LinvM, acc, p);
        if (p < 3) {
            int nt = 3 - p;
            k_cholu<<<dim3(nt * (nt + 1) / 2, 2), 256, 0, stream>>>(Kuu, M2, p);
        }
    }
    // off-diagonal Linv blocks: one launch, per-column serial chain in-block
    k_toff2<<<dim3(3, 2), 512, 0, stream>>>(Kuu, M2, LinvK, LinvM);

    k_trace<<<dim3(16, 16), 256, 0, stream>>>(LinvK, S, Tpart);
    k_final<<<1, 256, 0, stream>>>(LinvM, G, Tpart, acc, kvp, out);
}